// Round 15
// baseline (99.882 us; speedup 1.0000x reference)
//
#include <hip/hip_runtime.h>
#include <math.h>

// DigitCaps dynamic routing, B=256 R=1152 C=10 OUT=16 IN=8, fp32 in/out.
// Identity: b_ij(t) = dot(u_hat, Vsum), Vsum = sum of previous v.
// THIS ROUND: materialize u_hat in f16 ONCE (it0) instead of recomputing the
// W-dots 3x. U[1280][256][3 uint4][8 og] = 126 MB in ws (L3-resident).
// it1/it2 = caps_pass: streaming reader, 6 dwordx4/thread-row, logit =
// 1 FDOT2 per c (u,v both packed f16), DPP og-reduction, no LDS/DS/barriers.
// caps_first: stage all 4 W rows -> one vmcnt(0) -> compute, store U, s+=0.1u.
//
// ws: s_part[80][256][160] f32 (13.1MB) + Vsum (0.16MB) + W16 (3.28MB f16)
//     + U (125.8MB) = 142.4MB

typedef _Float16 h2 __attribute__((ext_vector_type(2)));
typedef _Float16 h4 __attribute__((ext_vector_type(4)));

#if __has_builtin(__builtin_amdgcn_fdot2)
#define FDOT2(a, b, c) __builtin_amdgcn_fdot2((a), (b), (c), false)
#else
static __device__ __forceinline__ float FDOT2(h2 a, h2 b, float c) {
    return c + (float)a.x * (float)b.x + (float)a.y * (float)b.y;
}
#endif

static __device__ __forceinline__ h2 CVTPK(float a, float b) {
#if __has_builtin(__builtin_amdgcn_cvt_pkrtz)
    return __builtin_bit_cast(h2, __builtin_amdgcn_cvt_pkrtz(a, b));
#else
    h2 r; r.x = (_Float16)a; r.y = (_Float16)b; return r;
#endif
}

#if __has_builtin(__builtin_amdgcn_rcpf)
#define FRCP(x) __builtin_amdgcn_rcpf(x)
#else
#define FRCP(x) (1.0f / (x))
#endif

#define BCH2(u) __builtin_bit_cast(h2, (u))
#define BCU(x)  __builtin_bit_cast(unsigned, (x))

// cross-lane add via DPP (VALU, not DS). 0xB1 = quad_perm xor1, 0x4E = xor2,
// 0x141 = ROW_HALF_MIRROR (completes the aligned-8-lane sum). Verified R9-R14.
template<int CTRL>
static __device__ __forceinline__ float dpp_xadd(float x) {
    const int t = __builtin_amdgcn_update_dpp(
        0, __builtin_bit_cast(int, x), CTRL, 0xF, 0xF, true);
    return x + __builtin_bit_cast(float, t);
}
static __device__ __forceinline__ float og_allsum(float l) {
    l = dpp_xadd<0xB1>(l);
    l = dpp_xadd<0x4E>(l);
    l = dpp_xadd<0x141>(l);
    return l;
}

namespace {
constexpr int Bdim = 256;
constexpr int Rdim = 1152;
constexpr int Cdim = 10;
constexpr int Odim = 16;
constexpr int Idim = 8;
constexpr int CO   = 160;

constexpr int Rpad = 1280;   // zero-padded R (pad rows: u=0 -> exact no-op)
constexpr int RPC  = 4;      // rows per chunk (= per wave)
constexpr int NQ   = 80;     // chunk-quads = s_part slices
constexpr int NSP  = 80;
constexpr int WROW = Cdim * Odim * Idim;   // 1280 f16 per W row
}

// f32 -> f16 W with zero padding to Rpad rows. Coalesced both sides.
__global__ __launch_bounds__(256)
void conv_w(const float* __restrict__ W, _Float16* __restrict__ W16)
{
    const int i = blockIdx.x * 256 + threadIdx.x;    // < 409600
    const int r = i / (WROW / 4);
    h4 o = { (_Float16)0.f, (_Float16)0.f, (_Float16)0.f, (_Float16)0.f };
    if (r < Rdim) {
        const float4 v = reinterpret_cast<const float4*>(W)[i];
        o = { (_Float16)v.x, (_Float16)v.y, (_Float16)v.z, (_Float16)v.w };
    }
    reinterpret_cast<h4*>(W16)[i] = o;
}

// Stage one W row-pair (2560 f16 = 5 KB) linearly into a wave-private buffer.
__device__ __forceinline__ void stagepair(const _Float16* __restrict__ src,
                                          _Float16* dst, int lane)
{
#pragma unroll
    for (int k = 0; k < 5; ++k) {
        const _Float16* s = src + (size_t)(k * 64 + lane) * 8;
        _Float16* d = dst + k * 512;
        __builtin_amdgcn_global_load_lds((const __attribute__((address_space(1))) void*)s,
                                         (__attribute__((address_space(3))) void*)d,
                                         16, 0, 0);
    }
}

// it0: compute u (f16 dots), store U, accumulate s with uniform c=0.1.
__global__ __launch_bounds__(256)
void caps_first(const float* __restrict__ xf, const _Float16* __restrict__ W16,
                uint4* __restrict__ U, float* __restrict__ s_part)
{
    __shared__ __align__(16) _Float16 Wst[4][RPC * WROW];   // 40960 B

    const int tid  = threadIdx.x;
    const int wv   = tid >> 6;
    const int lane = tid & 63;
    const int og   = lane & 7;
    const int bl   = lane >> 3;

    const int quad = blockIdx.x;        // 0..79
    const int bgrp = blockIdx.y;        // 0..15
    const int chunk = quad * 4 + wv;    // 0..319
    const int r0    = chunk * RPC;
    const int b0    = bgrp * 16 + bl;
    const int b1    = b0 + 8;

    float sA0[Cdim], sA1[Cdim], sB0[Cdim], sB1[Cdim];
#pragma unroll
    for (int c = 0; c < Cdim; ++c) { sA0[c]=0.f; sA1[c]=0.f; sB0[c]=0.f; sB1[c]=0.f; }

    // stage all 4 W rows + load all x upfront; single vmcnt(0)
    const _Float16* Wr = W16 + (size_t)r0 * WROW;
    stagepair(Wr, &Wst[wv][0], lane);
    stagepair(Wr + 2 * WROW, &Wst[wv][2 * WROW], lane);

    const float* xb0 = xf + (size_t)b0 * (Rdim * Idim);
    const float* xb1 = xf + (size_t)b1 * (Rdim * Idim);
    float4 xc[4][4];     // [row][A0,A1,B0,B1]
#pragma unroll
    for (int q = 0; q < 4; ++q) {
        int r = r0 + q;
        const int off = (r > Rdim - 1 ? Rdim - 1 : r) * Idim;   // clamp pads
        xc[q][0] = *reinterpret_cast<const float4*>(xb0 + off);
        xc[q][1] = *reinterpret_cast<const float4*>(xb0 + off + 4);
        xc[q][2] = *reinterpret_cast<const float4*>(xb1 + off);
        xc[q][3] = *reinterpret_cast<const float4*>(xb1 + off + 4);
    }
    asm volatile("s_waitcnt vmcnt(0)" ::: "memory");

#pragma unroll
    for (int q = 0; q < 4; ++q) {
        const int r = r0 + q;
        const h2 a0 = CVTPK(xc[q][0].x, xc[q][0].y), a1 = CVTPK(xc[q][0].z, xc[q][0].w);
        const h2 a2 = CVTPK(xc[q][1].x, xc[q][1].y), a3 = CVTPK(xc[q][1].z, xc[q][1].w);
        const h2 e0 = CVTPK(xc[q][2].x, xc[q][2].y), e1 = CVTPK(xc[q][2].z, xc[q][2].w);
        const h2 e2 = CVTPK(xc[q][3].x, xc[q][3].y), e3 = CVTPK(xc[q][3].z, xc[q][3].w);

        const _Float16* wbase = &Wst[wv][q * WROW] + og * 16;
        unsigned wA[Cdim], wB[Cdim];
#pragma unroll
        for (int c = 0; c < Cdim; ++c) {
            const uint4* wp = reinterpret_cast<const uint4*>(wbase + c * (Odim * Idim));
            const uint4 w0 = wp[0], w1 = wp[1];
            float t;
            float uA0, uA1, uB0, uB1;
            t = FDOT2(BCH2(w0.x), a0, 0.f);  t = FDOT2(BCH2(w0.y), a1, t);
            t = FDOT2(BCH2(w0.z), a2, t);    uA0 = FDOT2(BCH2(w0.w), a3, t);
            t = FDOT2(BCH2(w1.x), a0, 0.f);  t = FDOT2(BCH2(w1.y), a1, t);
            t = FDOT2(BCH2(w1.z), a2, t);    uA1 = FDOT2(BCH2(w1.w), a3, t);
            t = FDOT2(BCH2(w0.x), e0, 0.f);  t = FDOT2(BCH2(w0.y), e1, t);
            t = FDOT2(BCH2(w0.z), e2, t);    uB0 = FDOT2(BCH2(w0.w), e3, t);
            t = FDOT2(BCH2(w1.x), e0, 0.f);  t = FDOT2(BCH2(w1.y), e1, t);
            t = FDOT2(BCH2(w1.z), e2, t);    uB1 = FDOT2(BCH2(w1.w), e3, t);
            sA0[c] += 0.1f * uA0;  sA1[c] += 0.1f * uA1;
            sB0[c] += 0.1f * uB0;  sB1[c] += 0.1f * uB1;
            wA[c] = BCU(CVTPK(uA0, uA1));
            wB[c] = BCU(CVTPK(uB0, uB1));
        }

        // store U: layout [r][b][k(3 uint4)][og]; inst k = contiguous across og
        uint4* Ua = U + (((size_t)r * Bdim + b0) * 3) * 8 + og;
        uint4* Ub = U + (((size_t)r * Bdim + b1) * 3) * 8 + og;
        Ua[0]  = make_uint4(wA[0], wA[1], wA[2], wA[3]);
        Ua[8]  = make_uint4(wA[4], wA[5], wA[6], wA[7]);
        Ua[16] = make_uint4(wA[8], wA[9], 0u, 0u);
        Ub[0]  = make_uint4(wB[0], wB[1], wB[2], wB[3]);
        Ub[8]  = make_uint4(wB[4], wB[5], wB[6], wB[7]);
        Ub[16] = make_uint4(wB[8], wB[9], 0u, 0u);
    }

    // ---- in-block reduce over 4 waves (reuse Wst as f32 [4][16][160])
    __syncthreads();
    float* red = reinterpret_cast<float*>(&Wst[0][0]);
    {
        float* p0 = red + (wv * 16 + bl) * CO + og * 2;
        float* p1 = red + (wv * 16 + bl + 8) * CO + og * 2;
#pragma unroll
        for (int c = 0; c < Cdim; ++c) {
            *reinterpret_cast<float2*>(p0 + c * Odim) = make_float2(sA0[c], sA1[c]);
            *reinterpret_cast<float2*>(p1 + c * Odim) = make_float2(sB0[c], sB1[c]);
        }
    }
    __syncthreads();
#pragma unroll
    for (int k = 0; k < 10; ++k) {
        const int j = k * 256 + tid;
        const float t = red[j] + red[j + 2560] + red[j + 5120] + red[j + 7680];
        const int b2 = j / CO;
        const int co = j - b2 * CO;
        s_part[((size_t)quad * Bdim + bgrp * 16 + b2) * CO + co] = t;
    }
}

// it1/it2: stream U, softmax (logit = 1 FDOT2/c + DPP og-reduce), accumulate s.
__global__ __launch_bounds__(256)
void caps_pass(const uint4* __restrict__ U, const float* __restrict__ Vsum,
               float* __restrict__ s_part)
{
    __shared__ __align__(16) float red[4 * 16 * CO];   // 40960 B

    const int tid  = threadIdx.x;
    const int wv   = tid >> 6;
    const int lane = tid & 63;
    const int og   = lane & 7;
    const int bl   = lane >> 3;

    const int quad = blockIdx.x;
    const int bgrp = blockIdx.y;
    const int chunk = quad * 4 + wv;
    const int r0    = chunk * RPC;
    const int b0    = bgrp * 16 + bl;
    const int b1    = b0 + 8;

    // v packed to h2 (per c, this lane's o-pair)
    h2 vh0[Cdim], vh1[Cdim];
#pragma unroll
    for (int c = 0; c < Cdim; ++c) {
        const float2 p = *reinterpret_cast<const float2*>(
            Vsum + (size_t)b0 * CO + c * Odim + og * 2);
        vh0[c] = CVTPK(p.x, p.y);
        const float2 q = *reinterpret_cast<const float2*>(
            Vsum + (size_t)b1 * CO + c * Odim + og * 2);
        vh1[c] = CVTPK(q.x, q.y);
    }

    float sA0[Cdim], sA1[Cdim], sB0[Cdim], sB1[Cdim];
#pragma unroll
    for (int c = 0; c < Cdim; ++c) { sA0[c]=0.f; sA1[c]=0.f; sB0[c]=0.f; sB1[c]=0.f; }

#pragma unroll
    for (int q = 0; q < RPC; ++q) {
        const int r = r0 + q;
        const uint4* Ua = U + (((size_t)r * Bdim + b0) * 3) * 8 + og;
        const uint4* Ub = U + (((size_t)r * Bdim + b1) * 3) * 8 + og;
        const uint4 qa0 = Ua[0], qa1 = Ua[8], qa2 = Ua[16];
        const uint4 qb0 = Ub[0], qb1 = Ub[8], qb2 = Ub[16];
        const unsigned wa[Cdim] = { qa0.x, qa0.y, qa0.z, qa0.w,
                                    qa1.x, qa1.y, qa1.z, qa1.w, qa2.x, qa2.y };
        const unsigned wb[Cdim] = { qb0.x, qb0.y, qb0.z, qb0.w,
                                    qb1.x, qb1.y, qb1.z, qb1.w, qb2.x, qb2.y };

        float eA[Cdim], eB[Cdim];
        float sumA = 0.f, sumB = 0.f;
#pragma unroll
        for (int c = 0; c < Cdim; ++c) {
            float lA = FDOT2(BCH2(wa[c]), vh0[c], 0.f);
            lA = og_allsum(lA);                 // full 16-o logit (o-pair + 8 og)
            eA[c] = __expf(lA);  sumA += eA[c];
            float lB = FDOT2(BCH2(wb[c]), vh1[c], 0.f);
            lB = og_allsum(lB);
            eB[c] = __expf(lB);  sumB += eB[c];
        }
        const float rA = FRCP(sumA), rB = FRCP(sumB);
#pragma unroll
        for (int c = 0; c < Cdim; ++c) {
            const h2 ua = BCH2(wa[c]);
            const h2 ub = BCH2(wb[c]);
            const float cwA = eA[c] * rA;
            sA0[c] += cwA * (float)ua.x;  sA1[c] += cwA * (float)ua.y;
            const float cwB = eB[c] * rB;
            sB0[c] += cwB * (float)ub.x;  sB1[c] += cwB * (float)ub.y;
        }
    }

    // ---- in-block reduce over 4 waves
    __syncthreads();
    {
        float* p0 = red + (wv * 16 + bl) * CO + og * 2;
        float* p1 = red + (wv * 16 + bl + 8) * CO + og * 2;
#pragma unroll
        for (int c = 0; c < Cdim; ++c) {
            *reinterpret_cast<float2*>(p0 + c * Odim) = make_float2(sA0[c], sA1[c]);
            *reinterpret_cast<float2*>(p1 + c * Odim) = make_float2(sB0[c], sB1[c]);
        }
    }
    __syncthreads();
#pragma unroll
    for (int k = 0; k < 10; ++k) {
        const int j = k * 256 + tid;
        const float t = red[j] + red[j + 2560] + red[j + 5120] + red[j + 7680];
        const int b2 = j / CO;
        const int co = j - b2 * CO;
        s_part[((size_t)quad * Bdim + bgrp * 16 + b2) * CO + co] = t;
    }
}

// Sum the NSP partials, squash; MODE 0: Vsum = v, MODE 1: Vsum += v, MODE 2: out.
template<int MODE>
__global__ __launch_bounds__(256)
void caps_reduce(const float* __restrict__ s_part, float* __restrict__ Vsum,
                 float* __restrict__ out)
{
    const int idx = blockIdx.x * 256 + threadIdx.x;   // < 40960
    float s = 0.f;
#pragma unroll 8
    for (int k = 0; k < NSP; ++k) s += s_part[(size_t)k * (Bdim * CO) + idx];

    float ssq = s * s;
    ssq += __shfl_xor(ssq, 1);
    ssq += __shfl_xor(ssq, 2);
    ssq += __shfl_xor(ssq, 4);
    ssq += __shfl_xor(ssq, 8);

    const float mag = sqrtf(ssq + 1e-8f);
    const float v = ssq / (1.f + ssq) * s / (mag + 1e-8f);

    if constexpr (MODE == 2) out[idx] = v;
    else if constexpr (MODE == 1) Vsum[idx] += v;
    else Vsum[idx] = v;
}

extern "C" void kernel_launch(void* const* d_in, const int* in_sizes, int n_in,
                              void* d_out, int out_size, void* d_ws, size_t ws_size,
                              hipStream_t stream)
{
    const float* x = (const float*)d_in[0];   // [256,1152,8]
    const float* W = (const float*)d_in[1];   // [1152,10,16,8]
    float* out = (float*)d_out;               // [256,10,16]

    float* s_part = (float*)d_ws;                           // 80*256*160 f32
    float* Vsum   = s_part + (size_t)NSP * Bdim * CO;       // 256*160 f32
    _Float16* W16 = (_Float16*)(Vsum + Bdim * CO);          // 1280*1280 f16
    uint4* U      = (uint4*)(W16 + (size_t)Rpad * WROW);    // 1280*256*24 B*2

    conv_w<<<dim3(1600), dim3(256), 0, stream>>>(W, W16);

    const dim3 gi(NQ, Bdim / 16);    // (80, 16) = 1280 blocks, 4 waves each
    const dim3 bi(256);
    const dim3 gr((Bdim * CO) / 256);
    const dim3 br(256);

    // it 0: compute + materialize U
    caps_first<<<gi, bi, 0, stream>>>(x, W16, U, s_part);
    caps_reduce<0><<<gr, br, 0, stream>>>(s_part, Vsum, out);
    // it 1: stream U
    caps_pass<<<gi, bi, 0, stream>>>(U, Vsum, s_part);
    caps_reduce<1><<<gr, br, 0, stream>>>(s_part, Vsum, out);
    // it 2: stream U (final -> d_out)
    caps_pass<<<gi, bi, 0, stream>>>(U, Vsum, s_part);
    caps_reduce<2><<<gr, br, 0, stream>>>(s_part, Vsum, out);
}